// Round 1
// baseline (2808.091 us; speedup 1.0000x reference)
//
#include <hip/hip_runtime.h>
#include <hip/hip_bf16.h>
#include <math.h>

#define ROI   116
#define FEATN 6670        // ROI*(ROI-1)/2
#define KP    6688        // FEATN padded to multiple of 32
#define DD    1024
#define HHN   1024
#define BB    64
#define WW    128
#define MT    8192        // BB*WW
#define XW    7694        // HHN + FEATN
#define EPSV  1e-5f

typedef __attribute__((ext_vector_type(8))) short short8;
typedef __attribute__((ext_vector_type(4))) float f32x4;
typedef __attribute__((ext_vector_type(4))) unsigned int u32x4;

__device__ __forceinline__ short f2bf(float v) {
  __hip_bfloat16 b = __float2bfloat16(v);
  return *reinterpret_cast<short*>(&b);
}

__device__ __forceinline__ float fast_tanh(float x) {
  float ax = fabsf(x);
  float t  = __expf(-2.0f * ax);           // exp accurate to ~1e-6 rel; fine vs bf16 noise
  float r  = (1.0f - t) / (1.0f + t);
  return copysignf(r, x);
}

// ---- LUT: f -> (i,j) of triu(ROI, k=1), lexicographic ----
__global__ void k_lut(int2* lut) {
  int f = blockIdx.x * 256 + threadIdx.x;
  if (f >= FEATN) return;
  // start(i) = i*(231-i)/2 ; largest i with start(i) <= f
  int i = (int)((231.0 - sqrt((double)(53361 - 8 * f))) * 0.5);
  if (i < 0) i = 0;
  if (i > ROI - 2) i = ROI - 2;
  while (i > 0 && i * (231 - i) / 2 > f) --i;
  while (i < ROI - 2 && (i + 1) * (231 - (i + 1)) / 2 <= f) ++i;
  int j = i + 1 + (f - i * (231 - i) / 2);
  lut[f] = make_int2(i, j);
}

// ---- extract bag_level -> bf16 [MT][KP], zero-padded K ----
__global__ void k_extract(const float* __restrict__ FC, const int2* __restrict__ lut,
                          short* __restrict__ bag) {
  int m = blockIdx.x;                       // 0..8191
  const float* base = FC + (size_t)m * (ROI * ROI);
  for (int f = threadIdx.x; f < KP; f += 256) {
    float v = 0.f;
    if (f < FEATN) {
      int2 ij = lut[f];
      v = base[ij.x * ROI + ij.y];
    }
    bag[(size_t)m * KP + f] = f2bf(v);
  }
}

// ---- transpose W1 (FEAT x D fp32) -> W1T (D x KP bf16), zero-padded K ----
__global__ void k_transpose(const float* __restrict__ W1, short* __restrict__ W1T) {
  __shared__ float tile[32][33];
  int k0 = blockIdx.x * 32;                 // K dim (grid.x = KP/32 = 209)
  int d0 = blockIdx.y * 32;                 // D dim (grid.y = 32)
  int tx = threadIdx.x & 31, ty = threadIdx.x >> 5;   // 32 x 8
  for (int r = 0; r < 32; r += 8) {
    int k = k0 + ty + r;
    float v = 0.f;
    if (k < FEATN) v = W1[(size_t)k * DD + d0 + tx];
    tile[ty + r][tx] = v;
  }
  __syncthreads();
  for (int r = 0; r < 32; r += 8) {
    W1T[(size_t)(d0 + ty + r) * KP + k0 + tx] = f2bf(tile[tx][ty + r]);
  }
}

// ---- main GEMM: h = tanh(bag @ W1 + b1), bf16 MFMA 16x16x32, 128x128 tile ----
__global__ __launch_bounds__(256) void k_gemm(const short* __restrict__ A,
                                              const short* __restrict__ BT,
                                              const float* __restrict__ b1,
                                              float* __restrict__ Hout) {
  __shared__ __align__(16) short As[128][32];
  __shared__ __align__(16) short Bs[128][32];
  int tid  = threadIdx.x;
  int m0   = blockIdx.x * 128;
  int n0   = blockIdx.y * 128;
  int wave = tid >> 6, lane = tid & 63;
  int wr = wave >> 1, wc = wave & 1;        // 2x2 waves, each 64x64
  int quad = lane >> 4, l15 = lane & 15;
  int sr = tid >> 2;                        // staging row 0..63 (and +64)
  int sc = (tid & 3) * 8;                   // staging col (elems)

  f32x4 acc[4][4] = {};

  const short* Ag0 = A  + (size_t)(m0 + sr) * KP + sc;
  const short* Ag1 = Ag0 + (size_t)64 * KP;
  const short* Bg0 = BT + (size_t)(n0 + sr) * KP + sc;
  const short* Bg1 = Bg0 + (size_t)64 * KP;

  for (int k0 = 0; k0 < KP; k0 += 32) {
    *(u32x4*)(&As[sr][sc])      = *(const u32x4*)(Ag0 + k0);
    *(u32x4*)(&As[sr + 64][sc]) = *(const u32x4*)(Ag1 + k0);
    *(u32x4*)(&Bs[sr][sc])      = *(const u32x4*)(Bg0 + k0);
    *(u32x4*)(&Bs[sr + 64][sc]) = *(const u32x4*)(Bg1 + k0);
    __syncthreads();

    short8 af[4], bf[4];
#pragma unroll
    for (int mi = 0; mi < 4; mi++)
      af[mi] = *(const short8*)(&As[wr * 64 + mi * 16 + l15][quad * 8]);
#pragma unroll
    for (int ni = 0; ni < 4; ni++)
      bf[ni] = *(const short8*)(&Bs[wc * 64 + ni * 16 + l15][quad * 8]);
#pragma unroll
    for (int mi = 0; mi < 4; mi++)
#pragma unroll
      for (int ni = 0; ni < 4; ni++)
        acc[mi][ni] = __builtin_amdgcn_mfma_f32_16x16x32_bf16(af[mi], bf[ni], acc[mi][ni], 0, 0, 0);
    __syncthreads();
  }

  // epilogue: tanh(acc + b1[n]) -> Hout ; C/D layout: col=lane&15, row=quad*4+r
#pragma unroll
  for (int ni = 0; ni < 4; ni++) {
    int n = n0 + wc * 64 + ni * 16 + l15;
    float bias = b1[n];
#pragma unroll
    for (int mi = 0; mi < 4; mi++) {
#pragma unroll
      for (int r = 0; r < 4; r++) {
        int m = m0 + wr * 64 + mi * 16 + quad * 4 + r;
        Hout[(size_t)m * DD + n] = fast_tanh(acc[mi][ni][r] + bias);
      }
    }
  }
}

// ---- a[m] = h[m,:] @ W2 + b2 ----
__global__ void k_a(const float* __restrict__ H, const float* __restrict__ W2,
                    const float* __restrict__ b2, float* __restrict__ a) {
  int m = blockIdx.x, t = threadIdx.x;
  float s = 0.f;
  for (int n = t; n < DD; n += 256) s += H[(size_t)m * DD + n] * W2[n];
  __shared__ float red[256];
  red[t] = s; __syncthreads();
  for (int st = 128; st > 0; st >>= 1) {
    if (t < st) red[t] += red[t + st];
    __syncthreads();
  }
  if (t == 0) a[m] = red[0] + b2[0];
}

// ---- softmax over W per bag ----
__global__ void k_softmax(const float* __restrict__ a, float* __restrict__ att) {
  int b = blockIdx.x, t = threadIdx.x;      // 128 threads
  __shared__ float sh[128];
  float v = a[b * WW + t];
  sh[t] = v; __syncthreads();
  for (int s = 64; s > 0; s >>= 1) { if (t < s) sh[t] = fmaxf(sh[t], sh[t + s]); __syncthreads(); }
  float mx = sh[0]; __syncthreads();
  float e = expf(v - mx);
  sh[t] = e; __syncthreads();
  for (int s = 64; s > 0; s >>= 1) { if (t < s) sh[t] += sh[t + s]; __syncthreads(); }
  att[b * WW + t] = e / sh[0];
}

// ---- bag_z_up[b][f] = sum_w att[b,w] * FC[b,w,iu0,iu1] (fp32 gather) ----
__global__ void k_bagz(const float* __restrict__ FC, const int2* __restrict__ lut,
                       const float* __restrict__ att, float* __restrict__ bagz) {
  __shared__ float atts[WW];
  int b = blockIdx.y;
  int f = blockIdx.x * 256 + threadIdx.x;
  if (threadIdx.x < WW) atts[threadIdx.x] = att[b * WW + threadIdx.x];
  __syncthreads();
  if (f >= FEATN) return;
  int2 ij = lut[f];
  const float* base = FC + (size_t)b * WW * ROI * ROI + ij.x * ROI + ij.y;
  float s = 0.f;
  for (int w = 0; w < WW; ++w) s += atts[w] * base[(size_t)w * ROI * ROI];
  bagz[(size_t)b * FEATN + f] = s;
}

// ---- batchnorm over batch(64), write into X[:, HHN + f] ----
__global__ void k_bn(const float* __restrict__ bagz, const float* __restrict__ g,
                     const float* __restrict__ beta, float* __restrict__ X) {
  int f = blockIdx.x * 256 + threadIdx.x;
  if (f >= FEATN) return;
  float s = 0.f, s2 = 0.f;
  for (int b = 0; b < BB; b++) { float v = bagz[(size_t)b * FEATN + f]; s += v; s2 += v * v; }
  float mu  = s * (1.f / BB);
  float var = s2 * (1.f / BB) - mu * mu;
  float sc  = rsqrtf(var + EPSV) * g[f];
  float bt  = beta[f];
  for (int b = 0; b < BB; b++)
    X[(size_t)b * XW + HHN + f] = (bagz[(size_t)b * FEATN + f] - mu) * sc + bt;
}

// ---- batchnorm cluster_centers (2 rows) ----
__global__ void k_ccbn(const float* __restrict__ cc, const float* __restrict__ g,
                       const float* __restrict__ beta, float* __restrict__ ccbn) {
  int f = blockIdx.x * 256 + threadIdx.x;
  if (f >= FEATN) return;
  float c0 = cc[f], c1 = cc[FEATN + f];
  float mu = 0.5f * (c0 + c1);
  float d0 = c0 - mu, d1 = c1 - mu;
  float var = 0.5f * (d0 * d0 + d1 * d1);
  float sc = rsqrtf(var + EPSV) * g[f];
  ccbn[f]         = d0 * sc + beta[f];
  ccbn[FEATN + f] = d1 * sc + beta[f];
}

// ---- skinny fp32 GEMM: partial[ky][r][n] = sum_{k in chunk} Z[r][k] * Wt[k][n] ----
// MODE 0: Z = [X[:, HHN:] (64 rows), ccbn (2 rows)]  (K=FEATN)
// MODE 1: Z = ccbn (2 rows)                          (K=FEATN)
// MODE 2: Z = X (64 rows)                            (K=XW)
template <int R, int MODE>
__global__ void k_skinny(const float* __restrict__ X, const float* __restrict__ ccbn,
                         const float* __restrict__ Wt, float* __restrict__ partial,
                         int K, int kchunk) {
  __shared__ __align__(16) float zs[R][64];
  int n  = blockIdx.x * 256 + threadIdx.x;  // grid.x = 4 -> n < 1024
  int k0 = blockIdx.y * kchunk;
  int k1 = min(k0 + kchunk, K);
  float acc[R];
#pragma unroll
  for (int r = 0; r < R; r++) acc[r] = 0.f;

  for (int kk0 = k0; kk0 < k1; kk0 += 64) {
    for (int idx = threadIdx.x; idx < R * 64; idx += 256) {
      int r = idx >> 6, c = idx & 63;
      int k = kk0 + c;
      float v = 0.f;
      if (k < k1) {
        const float* zr;
        if (MODE == 0) zr = (r < 64) ? (X + (size_t)r * XW + HHN) : (ccbn + (size_t)(r - 64) * FEATN);
        else if (MODE == 1) zr = ccbn + (size_t)r * FEATN;
        else zr = X + (size_t)r * XW;
        v = zr[k];
      }
      zs[r][c] = v;
    }
    __syncthreads();
#pragma unroll 4
    for (int cq = 0; cq < 16; ++cq) {
      int k = kk0 + cq * 4;
      float w0 = (k + 0 < k1) ? Wt[(size_t)(k + 0) * HHN + n] : 0.f;
      float w1 = (k + 1 < k1) ? Wt[(size_t)(k + 1) * HHN + n] : 0.f;
      float w2 = (k + 2 < k1) ? Wt[(size_t)(k + 2) * HHN + n] : 0.f;
      float w3 = (k + 3 < k1) ? Wt[(size_t)(k + 3) * HHN + n] : 0.f;
#pragma unroll
      for (int r = 0; r < R; r++) {
        f32x4 z = *(const f32x4*)(&zs[r][cq * 4]);
        acc[r] += z.x * w0 + z.y * w1 + z.z * w2 + z.w * w3;
      }
    }
    __syncthreads();
  }
#pragma unroll
  for (int r = 0; r < R; r++)
    partial[(size_t)blockIdx.y * R * HHN + (size_t)r * HHN + n] = acc[r];
}

// ---- reduce split-K partials, add bias, optional relu ----
template <int R>
__global__ void k_reduce(const float* __restrict__ partial, const float* __restrict__ bias,
                         float* __restrict__ out, int KB, int act) {
  int idx = blockIdx.x * 256 + threadIdx.x;
  if (idx >= R * HHN) return;
  int n = idx & (HHN - 1);
  float s = bias[n];
  for (int kb = 0; kb < KB; kb++) s += partial[(size_t)kb * R * HHN + idx];
  if (act) s = fmaxf(s, 0.f);
  out[idx] = s;
}

// ---- cross attention: QK softmax over 2 centers, write final_cross into X[:, :HHN] ----
__global__ void k_cross(const float* __restrict__ qv, const float* __restrict__ kb,
                        float* __restrict__ X) {
  int b = blockIdx.x, t = threadIdx.x;      // 256 threads
  const float* q  = qv + (size_t)b * HHN;
  const float* v0 = qv + (size_t)64 * HHN;
  const float* v1 = qv + (size_t)65 * HHN;
  float s0 = 0.f, s1 = 0.f;
  for (int n = t; n < HHN; n += 256) {
    float qn = q[n];
    s0 += qn * kb[n];
    s1 += qn * kb[HHN + n];
  }
  __shared__ float r0[256], r1[256];
  r0[t] = s0; r1[t] = s1; __syncthreads();
  for (int st = 128; st > 0; st >>= 1) {
    if (t < st) { r0[t] += r0[t + st]; r1[t] += r1[t + st]; }
    __syncthreads();
  }
  float d0 = r0[0] * (1.f / 32.f), d1 = r1[0] * (1.f / 32.f);   // /sqrt(1024)
  float mx = fmaxf(d0, d1);
  float e0 = expf(d0 - mx), e1 = expf(d1 - mx);
  float p0 = e0 / (e0 + e1), p1 = e1 / (e0 + e1);
  for (int n = t; n < HHN; n += 256)
    X[(size_t)b * XW + n] = p0 * v0[n] + p1 * v1[n];
}

// ---- final: y = relu_out @ Wc2 + bc2 -> sigmoid -> (prob, hat) ----
__global__ void k_final(const float* __restrict__ Rb, const float* __restrict__ Wc2,
                        const float* __restrict__ bc2, float* __restrict__ out) {
  int b = blockIdx.x, t = threadIdx.x;
  float s = 0.f;
  for (int n = t; n < HHN; n += 256) s += Rb[(size_t)b * HHN + n] * Wc2[n];
  __shared__ float red[256];
  red[t] = s; __syncthreads();
  for (int st = 128; st > 0; st >>= 1) {
    if (t < st) red[t] += red[t + st];
    __syncthreads();
  }
  if (t == 0) {
    float y = red[0] + bc2[0];
    float p = 1.f / (1.f + expf(-y));
    out[b]      = p;
    out[64 + b] = (p >= 0.5f) ? 1.f : 0.f;
  }
}

extern "C" void kernel_launch(void* const* d_in, const int* in_sizes, int n_in,
                              void* d_out, int out_size, void* d_ws, size_t ws_size,
                              hipStream_t stream) {
  const float* FC    = (const float*)d_in[0];
  const float* CC    = (const float*)d_in[1];
  const float* W1    = (const float*)d_in[2];
  const float* b1    = (const float*)d_in[3];
  const float* W2    = (const float*)d_in[4];
  const float* b2    = (const float*)d_in[5];
  const float* bn_g  = (const float*)d_in[6];
  const float* bn_b  = (const float*)d_in[7];
  const float* bn2_g = (const float*)d_in[8];
  const float* bn2_b = (const float*)d_in[9];
  const float* Wq    = (const float*)d_in[10];
  const float* bq    = (const float*)d_in[11];
  const float* Wk    = (const float*)d_in[12];
  const float* bk    = (const float*)d_in[13];
  const float* Wc1   = (const float*)d_in[14];
  const float* bc1   = (const float*)d_in[15];
  const float* Wc2   = (const float*)d_in[16];
  const float* bc2   = (const float*)d_in[17];
  float* out = (float*)d_out;

  char* w = (char*)d_ws;
  auto alloc = [&](size_t bytes) {
    char* p = w;
    w += (bytes + 255) & ~(size_t)255;
    return p;
  };
  short* bagbf   = (short*)alloc((size_t)MT * KP * 2);        // 109.6 MB
  short* W1T     = (short*)alloc((size_t)DD * KP * 2);        // 13.7 MB
  float* Hbuf    = (float*)alloc((size_t)MT * DD * 4);        // 33.6 MB
  float* abuf    = (float*)alloc((size_t)MT * 4);
  float* attbuf  = (float*)alloc((size_t)MT * 4);
  float* bagz    = (float*)alloc((size_t)BB * FEATN * 4);
  float* Xbuf    = (float*)alloc((size_t)BB * XW * 4);
  float* ccbn    = (float*)alloc((size_t)2 * FEATN * 4);
  float* qvbuf   = (float*)alloc((size_t)66 * HHN * 4);
  float* kbuf    = (float*)alloc((size_t)2 * HHN * 4);
  float* Rbuf    = (float*)alloc((size_t)BB * HHN * 4);
  int2*  lut     = (int2*)alloc((size_t)FEATN * 8);
  float* partQ   = (float*)alloc((size_t)64 * 66 * HHN * 4);  // 17.3 MB (reused as partC)
  float* partK   = (float*)alloc((size_t)64 * 2 * HHN * 4);
  float* partC   = partQ;                                     // alias: partQ dead before partC written

  k_lut<<<dim3((FEATN + 255) / 256), dim3(256), 0, stream>>>(lut);
  k_extract<<<dim3(MT), dim3(256), 0, stream>>>(FC, lut, bagbf);
  k_transpose<<<dim3(KP / 32, DD / 32), dim3(256), 0, stream>>>(W1, W1T);
  k_gemm<<<dim3(MT / 128, DD / 128), dim3(256), 0, stream>>>(bagbf, W1T, b1, Hbuf);
  k_a<<<dim3(MT), dim3(256), 0, stream>>>(Hbuf, W2, b2, abuf);
  k_softmax<<<dim3(BB), dim3(WW), 0, stream>>>(abuf, attbuf);
  k_bagz<<<dim3((FEATN + 255) / 256, BB), dim3(256), 0, stream>>>(FC, lut, attbuf, bagz);
  k_bn<<<dim3((FEATN + 255) / 256), dim3(256), 0, stream>>>(bagz, bn_g, bn_b, Xbuf);
  k_ccbn<<<dim3((FEATN + 255) / 256), dim3(256), 0, stream>>>(CC, bn2_g, bn2_b, ccbn);

  // q (rows 0..63) and v (rows 64..65) share Wq
  k_skinny<66, 0><<<dim3(4, 64), dim3(256), 0, stream>>>(Xbuf, ccbn, Wq, partQ, FEATN, 105);
  k_reduce<66><<<dim3(66 * HHN / 256), dim3(256), 0, stream>>>(partQ, bq, qvbuf, 64, 0);
  k_skinny<2, 1><<<dim3(4, 64), dim3(256), 0, stream>>>(Xbuf, ccbn, Wk, partK, FEATN, 105);
  k_reduce<2><<<dim3(2 * HHN / 256), dim3(256), 0, stream>>>(partK, bk, kbuf, 64, 0);
  k_cross<<<dim3(BB), dim3(256), 0, stream>>>(qvbuf, kbuf, Xbuf);

  k_skinny<64, 2><<<dim3(4, 64), dim3(256), 0, stream>>>(Xbuf, ccbn, Wc1, partC, XW, 121);
  k_reduce<64><<<dim3(64 * HHN / 256), dim3(256), 0, stream>>>(partC, bc1, Rbuf, 64, 1);
  k_final<<<dim3(BB), dim3(256), 0, stream>>>(Rbuf, Wc2, bc2, out);

  (void)in_sizes; (void)n_in; (void)out_size; (void)ws_size;
}

// Round 2
// 1229.477 us; speedup vs baseline: 2.2840x; 2.2840x over previous
//
#include <hip/hip_runtime.h>
#include <hip/hip_bf16.h>
#include <math.h>

#define ROI   116
#define FEATN 6670        // ROI*(ROI-1)/2
#define KP    6688        // FEATN padded to multiple of 32
#define DD    1024
#define HHN   1024
#define BB    64
#define WW    128
#define MT    8192        // BB*WW
#define XW    7694        // HHN + FEATN
#define EPSV  1e-5f
#define KB_SPLIT 32       // split-K blocks for skinny GEMMs

typedef __attribute__((ext_vector_type(8))) short short8;
typedef __attribute__((ext_vector_type(4))) float f32x4;
typedef __attribute__((ext_vector_type(4))) unsigned int u32x4;

__device__ __forceinline__ short f2bf(float v) {
  __hip_bfloat16 b = __float2bfloat16(v);
  return *reinterpret_cast<short*>(&b);
}

__device__ __forceinline__ float fast_tanh(float x) {
  float ax = fabsf(x);
  float t  = __expf(-2.0f * ax);
  float r  = (1.0f - t) / (1.0f + t);
  return copysignf(r, x);
}

// ---- LUT: f -> (i,j) of triu(ROI, k=1), lexicographic ----
__global__ void k_lut(int2* lut) {
  int f = blockIdx.x * 256 + threadIdx.x;
  if (f >= FEATN) return;
  int i = (int)((231.0 - sqrt((double)(53361 - 8 * f))) * 0.5);
  if (i < 0) i = 0;
  if (i > ROI - 2) i = ROI - 2;
  while (i > 0 && i * (231 - i) / 2 > f) --i;
  while (i < ROI - 2 && (i + 1) * (231 - (i + 1)) / 2 <= f) ++i;
  int j = i + 1 + (f - i * (231 - i) / 2);
  lut[f] = make_int2(i, j);
}

// ---- extract bag_level -> bf16 [MT][KP], zero-padded K ----
__global__ void k_extract(const float* __restrict__ FC, const int2* __restrict__ lut,
                          short* __restrict__ bag) {
  int m = blockIdx.x;
  const float* base = FC + (size_t)m * (ROI * ROI);
  for (int f = threadIdx.x; f < KP; f += 256) {
    float v = 0.f;
    if (f < FEATN) {
      int2 ij = lut[f];
      v = base[ij.x * ROI + ij.y];
    }
    bag[(size_t)m * KP + f] = f2bf(v);
  }
}

// ---- transpose W1 (FEAT x D fp32) -> W1T (D x KP bf16), zero-padded K ----
__global__ void k_transpose(const float* __restrict__ W1, short* __restrict__ W1T) {
  __shared__ float tile[32][33];
  int k0 = blockIdx.x * 32;
  int d0 = blockIdx.y * 32;
  int tx = threadIdx.x & 31, ty = threadIdx.x >> 5;
  for (int r = 0; r < 32; r += 8) {
    int k = k0 + ty + r;
    float v = 0.f;
    if (k < FEATN) v = W1[(size_t)k * DD + d0 + tx];
    tile[ty + r][tx] = v;
  }
  __syncthreads();
  for (int r = 0; r < 32; r += 8) {
    W1T[(size_t)(d0 + ty + r) * KP + k0 + tx] = f2bf(tile[tx][ty + r]);
  }
}

// ---- main GEMM: h = tanh(bag @ W1 + b1), bf16 MFMA 16x16x32, 128x128 tile ----
__global__ __launch_bounds__(256) void k_gemm(const short* __restrict__ A,
                                              const short* __restrict__ BT,
                                              const float* __restrict__ b1,
                                              float* __restrict__ Hout) {
  __shared__ __align__(16) short As[128][32];
  __shared__ __align__(16) short Bs[128][32];
  int tid  = threadIdx.x;
  int m0   = blockIdx.x * 128;
  int n0   = blockIdx.y * 128;
  int wave = tid >> 6, lane = tid & 63;
  int wr = wave >> 1, wc = wave & 1;
  int quad = lane >> 4, l15 = lane & 15;
  int sr = tid >> 2;
  int sc = (tid & 3) * 8;

  f32x4 acc[4][4] = {};

  const short* Ag0 = A  + (size_t)(m0 + sr) * KP + sc;
  const short* Ag1 = Ag0 + (size_t)64 * KP;
  const short* Bg0 = BT + (size_t)(n0 + sr) * KP + sc;
  const short* Bg1 = Bg0 + (size_t)64 * KP;

  for (int k0 = 0; k0 < KP; k0 += 32) {
    *(u32x4*)(&As[sr][sc])      = *(const u32x4*)(Ag0 + k0);
    *(u32x4*)(&As[sr + 64][sc]) = *(const u32x4*)(Ag1 + k0);
    *(u32x4*)(&Bs[sr][sc])      = *(const u32x4*)(Bg0 + k0);
    *(u32x4*)(&Bs[sr + 64][sc]) = *(const u32x4*)(Bg1 + k0);
    __syncthreads();

    short8 af[4], bf[4];
#pragma unroll
    for (int mi = 0; mi < 4; mi++)
      af[mi] = *(const short8*)(&As[wr * 64 + mi * 16 + l15][quad * 8]);
#pragma unroll
    for (int ni = 0; ni < 4; ni++)
      bf[ni] = *(const short8*)(&Bs[wc * 64 + ni * 16 + l15][quad * 8]);
#pragma unroll
    for (int mi = 0; mi < 4; mi++)
#pragma unroll
      for (int ni = 0; ni < 4; ni++)
        acc[mi][ni] = __builtin_amdgcn_mfma_f32_16x16x32_bf16(af[mi], bf[ni], acc[mi][ni], 0, 0, 0);
    __syncthreads();
  }

#pragma unroll
  for (int ni = 0; ni < 4; ni++) {
    int n = n0 + wc * 64 + ni * 16 + l15;
    float bias = b1[n];
#pragma unroll
    for (int mi = 0; mi < 4; mi++) {
#pragma unroll
      for (int r = 0; r < 4; r++) {
        int m = m0 + wr * 64 + mi * 16 + quad * 4 + r;
        Hout[(size_t)m * DD + n] = fast_tanh(acc[mi][ni][r] + bias);
      }
    }
  }
}

// ---- a[m] = h[m,:] @ W2 + b2 ----
__global__ void k_a(const float* __restrict__ H, const float* __restrict__ W2,
                    const float* __restrict__ b2, float* __restrict__ a) {
  int m = blockIdx.x, t = threadIdx.x;
  float s = 0.f;
  for (int n = t; n < DD; n += 256) s += H[(size_t)m * DD + n] * W2[n];
  __shared__ float red[256];
  red[t] = s; __syncthreads();
  for (int st = 128; st > 0; st >>= 1) {
    if (t < st) red[t] += red[t + st];
    __syncthreads();
  }
  if (t == 0) a[m] = red[0] + b2[0];
}

// ---- softmax over W per bag ----
__global__ void k_softmax(const float* __restrict__ a, float* __restrict__ att) {
  int b = blockIdx.x, t = threadIdx.x;
  __shared__ float sh[128];
  float v = a[b * WW + t];
  sh[t] = v; __syncthreads();
  for (int s = 64; s > 0; s >>= 1) { if (t < s) sh[t] = fmaxf(sh[t], sh[t + s]); __syncthreads(); }
  float mx = sh[0]; __syncthreads();
  float e = expf(v - mx);
  sh[t] = e; __syncthreads();
  for (int s = 64; s > 0; s >>= 1) { if (t < s) sh[t] += sh[t + s]; __syncthreads(); }
  att[b * WW + t] = e / sh[0];
}

// ---- bag_z_up[b][f] = sum_w att[b,w] * FC[b,w,iu0,iu1] (fp32 gather) ----
__global__ void k_bagz(const float* __restrict__ FC, const int2* __restrict__ lut,
                       const float* __restrict__ att, float* __restrict__ bagz) {
  __shared__ float atts[WW];
  int b = blockIdx.y;
  int f = blockIdx.x * 256 + threadIdx.x;
  if (threadIdx.x < WW) atts[threadIdx.x] = att[b * WW + threadIdx.x];
  __syncthreads();
  if (f >= FEATN) return;
  int2 ij = lut[f];
  const float* base = FC + (size_t)b * WW * ROI * ROI + ij.x * ROI + ij.y;
  float s = 0.f;
  for (int w = 0; w < WW; ++w) s += atts[w] * base[(size_t)w * ROI * ROI];
  bagz[(size_t)b * FEATN + f] = s;
}

// ---- batchnorm over batch(64), write into X[:, HHN + f] ----
__global__ void k_bn(const float* __restrict__ bagz, const float* __restrict__ g,
                     const float* __restrict__ beta, float* __restrict__ X) {
  int f = blockIdx.x * 256 + threadIdx.x;
  if (f >= FEATN) return;
  float s = 0.f, s2 = 0.f;
  for (int b = 0; b < BB; b++) { float v = bagz[(size_t)b * FEATN + f]; s += v; s2 += v * v; }
  float mu  = s * (1.f / BB);
  float var = s2 * (1.f / BB) - mu * mu;
  float sc  = rsqrtf(var + EPSV) * g[f];
  float bt  = beta[f];
  for (int b = 0; b < BB; b++)
    X[(size_t)b * XW + HHN + f] = (bagz[(size_t)b * FEATN + f] - mu) * sc + bt;
}

// ---- batchnorm cluster_centers (2 rows) ----
__global__ void k_ccbn(const float* __restrict__ cc, const float* __restrict__ g,
                       const float* __restrict__ beta, float* __restrict__ ccbn) {
  int f = blockIdx.x * 256 + threadIdx.x;
  if (f >= FEATN) return;
  float c0 = cc[f], c1 = cc[FEATN + f];
  float mu = 0.5f * (c0 + c1);
  float d0 = c0 - mu, d1 = c1 - mu;
  float var = 0.5f * (d0 * d0 + d1 * d1);
  float sc = rsqrtf(var + EPSV) * g[f];
  ccbn[f]         = d0 * sc + beta[f];
  ccbn[FEATN + f] = d1 * sc + beta[f];
}

// ---- skinny fp32 GEMM, spill-free: 64 n-cols x 4 row-groups per block ----
// partial[ky][r][n] = sum_{k in chunk} Z[r][k] * Wt[k][n]
// MODE 0: Z = [X[:, HHN:] (64 rows), ccbn (2 rows)]  (K=FEATN)
// MODE 1: Z = ccbn (2 rows)                          (K=FEATN)
// MODE 2: Z = X (64 rows)                            (K=XW)
// Per-thread acc = ceil(R/4) <= 17 regs -> no scratch spill (R1 fix:
// previous version held acc[R] per thread -> 2.7 GB scratch traffic).
template <int R, int MODE>
__global__ __launch_bounds__(256) void k_skinny(const float* __restrict__ X,
                                                const float* __restrict__ ccbn,
                                                const float* __restrict__ Wt,
                                                float* __restrict__ partial,
                                                int K, int kchunk) {
  constexpr int RG = (R + 3) / 4;           // rows per group
  constexpr int RP = RG * 4;                // padded row count
  __shared__ __align__(16) float zs[RP][68];  // row stride 272 B = 17*16 (aligned f32x4)
  int tx = threadIdx.x & 63;                // n within 64-tile
  int ty = threadIdx.x >> 6;                // row group 0..3
  int n  = blockIdx.x * 64 + tx;            // grid.x = 16
  int k0 = blockIdx.y * kchunk;
  int k1 = min(k0 + kchunk, K);
  int r0 = ty * RG;

  float acc[RG];
#pragma unroll
  for (int i = 0; i < RG; i++) acc[i] = 0.f;

  for (int kk0 = k0; kk0 < k1; kk0 += 64) {
    // stage Z[RP][64] (zeros beyond R rows / k1)
    for (int idx = threadIdx.x; idx < RP * 64; idx += 256) {
      int r = idx >> 6, c = idx & 63;
      int k = kk0 + c;
      float v = 0.f;
      if (r < R && k < k1) {
        const float* zr;
        if (MODE == 0) zr = (r < 64) ? (X + (size_t)r * XW + HHN) : (ccbn + (size_t)(r - 64) * FEATN);
        else if (MODE == 1) zr = ccbn + (size_t)r * FEATN;
        else zr = X + (size_t)r * XW;
        v = zr[k];
      }
      zs[r][c] = v;
    }
    __syncthreads();
#pragma unroll 4
    for (int c = 0; c < 64; c += 4) {
      int k = kk0 + c;
      float w0 = (k + 0 < k1) ? Wt[(size_t)(k + 0) * HHN + n] : 0.f;
      float w1 = (k + 1 < k1) ? Wt[(size_t)(k + 1) * HHN + n] : 0.f;
      float w2 = (k + 2 < k1) ? Wt[(size_t)(k + 2) * HHN + n] : 0.f;
      float w3 = (k + 3 < k1) ? Wt[(size_t)(k + 3) * HHN + n] : 0.f;
#pragma unroll
      for (int i = 0; i < RG; i++) {
        f32x4 z = *(const f32x4*)(&zs[r0 + i][c]);   // broadcast: no bank conflict
        acc[i] += z.x * w0 + z.y * w1 + z.z * w2 + z.w * w3;
      }
    }
    __syncthreads();
  }
#pragma unroll
  for (int i = 0; i < RG; i++) {
    int rr = r0 + i;
    if (rr < R)
      partial[(size_t)blockIdx.y * R * HHN + (size_t)rr * HHN + n] = acc[i];
  }
}

// ---- reduce split-K partials, add bias, optional relu ----
template <int R>
__global__ void k_reduce(const float* __restrict__ partial, const float* __restrict__ bias,
                         float* __restrict__ out, int KB, int act) {
  int idx = blockIdx.x * 256 + threadIdx.x;
  if (idx >= R * HHN) return;
  int n = idx & (HHN - 1);
  float s = bias[n];
  for (int kb = 0; kb < KB; kb++) s += partial[(size_t)kb * R * HHN + idx];
  if (act) s = fmaxf(s, 0.f);
  out[idx] = s;
}

// ---- cross attention: QK softmax over 2 centers, write final_cross into X[:, :HHN] ----
__global__ void k_cross(const float* __restrict__ qv, const float* __restrict__ kb,
                        float* __restrict__ X) {
  int b = blockIdx.x, t = threadIdx.x;
  const float* q  = qv + (size_t)b * HHN;
  const float* v0 = qv + (size_t)64 * HHN;
  const float* v1 = qv + (size_t)65 * HHN;
  float s0 = 0.f, s1 = 0.f;
  for (int n = t; n < HHN; n += 256) {
    float qn = q[n];
    s0 += qn * kb[n];
    s1 += qn * kb[HHN + n];
  }
  __shared__ float r0[256], r1[256];
  r0[t] = s0; r1[t] = s1; __syncthreads();
  for (int st = 128; st > 0; st >>= 1) {
    if (t < st) { r0[t] += r0[t + st]; r1[t] += r1[t + st]; }
    __syncthreads();
  }
  float d0 = r0[0] * (1.f / 32.f), d1 = r1[0] * (1.f / 32.f);
  float mx = fmaxf(d0, d1);
  float e0 = expf(d0 - mx), e1 = expf(d1 - mx);
  float p0 = e0 / (e0 + e1), p1 = e1 / (e0 + e1);
  for (int n = t; n < HHN; n += 256)
    X[(size_t)b * XW + n] = p0 * v0[n] + p1 * v1[n];
}

// ---- final: y = relu_out @ Wc2 + bc2 -> sigmoid -> (prob, hat) ----
__global__ void k_final(const float* __restrict__ Rb, const float* __restrict__ Wc2,
                        const float* __restrict__ bc2, float* __restrict__ out) {
  int b = blockIdx.x, t = threadIdx.x;
  float s = 0.f;
  for (int n = t; n < HHN; n += 256) s += Rb[(size_t)b * HHN + n] * Wc2[n];
  __shared__ float red[256];
  red[t] = s; __syncthreads();
  for (int st = 128; st > 0; st >>= 1) {
    if (t < st) red[t] += red[t + st];
    __syncthreads();
  }
  if (t == 0) {
    float y = red[0] + bc2[0];
    float p = 1.f / (1.f + expf(-y));
    out[b]      = p;
    out[64 + b] = (p >= 0.5f) ? 1.f : 0.f;
  }
}

extern "C" void kernel_launch(void* const* d_in, const int* in_sizes, int n_in,
                              void* d_out, int out_size, void* d_ws, size_t ws_size,
                              hipStream_t stream) {
  const float* FC    = (const float*)d_in[0];
  const float* CC    = (const float*)d_in[1];
  const float* W1    = (const float*)d_in[2];
  const float* b1    = (const float*)d_in[3];
  const float* W2    = (const float*)d_in[4];
  const float* b2    = (const float*)d_in[5];
  const float* bn_g  = (const float*)d_in[6];
  const float* bn_b  = (const float*)d_in[7];
  const float* bn2_g = (const float*)d_in[8];
  const float* bn2_b = (const float*)d_in[9];
  const float* Wq    = (const float*)d_in[10];
  const float* bq    = (const float*)d_in[11];
  const float* Wk    = (const float*)d_in[12];
  const float* bk    = (const float*)d_in[13];
  const float* Wc1   = (const float*)d_in[14];
  const float* bc1   = (const float*)d_in[15];
  const float* Wc2   = (const float*)d_in[16];
  const float* bc2   = (const float*)d_in[17];
  float* out = (float*)d_out;

  char* w = (char*)d_ws;
  auto alloc = [&](size_t bytes) {
    char* p = w;
    w += (bytes + 255) & ~(size_t)255;
    return p;
  };
  short* bagbf   = (short*)alloc((size_t)MT * KP * 2);        // 109.6 MB
  short* W1T     = (short*)alloc((size_t)DD * KP * 2);        // 13.7 MB
  float* Hbuf    = (float*)alloc((size_t)MT * DD * 4);        // 33.6 MB
  float* abuf    = (float*)alloc((size_t)MT * 4);
  float* attbuf  = (float*)alloc((size_t)MT * 4);
  float* bagz    = (float*)alloc((size_t)BB * FEATN * 4);
  float* Xbuf    = (float*)alloc((size_t)BB * XW * 4);
  float* ccbn    = (float*)alloc((size_t)2 * FEATN * 4);
  float* qvbuf   = (float*)alloc((size_t)66 * HHN * 4);
  float* kbuf    = (float*)alloc((size_t)2 * HHN * 4);
  float* Rbuf    = (float*)alloc((size_t)BB * HHN * 4);
  int2*  lut     = (int2*)alloc((size_t)FEATN * 8);
  float* partQ   = (float*)alloc((size_t)KB_SPLIT * 66 * HHN * 4);  // 8.65 MB (reused as partC)
  float* partK   = (float*)alloc((size_t)KB_SPLIT * 2 * HHN * 4);
  float* partC   = partQ;                                     // alias: partQ dead before partC written

  k_lut<<<dim3((FEATN + 255) / 256), dim3(256), 0, stream>>>(lut);
  k_extract<<<dim3(MT), dim3(256), 0, stream>>>(FC, lut, bagbf);
  k_transpose<<<dim3(KP / 32, DD / 32), dim3(256), 0, stream>>>(W1, W1T);
  k_gemm<<<dim3(MT / 128, DD / 128), dim3(256), 0, stream>>>(bagbf, W1T, b1, Hbuf);
  k_a<<<dim3(MT), dim3(256), 0, stream>>>(Hbuf, W2, b2, abuf);
  k_softmax<<<dim3(BB), dim3(WW), 0, stream>>>(abuf, attbuf);
  k_bagz<<<dim3((FEATN + 255) / 256, BB), dim3(256), 0, stream>>>(FC, lut, attbuf, bagz);
  k_bn<<<dim3((FEATN + 255) / 256), dim3(256), 0, stream>>>(bagz, bn_g, bn_b, Xbuf);
  k_ccbn<<<dim3((FEATN + 255) / 256), dim3(256), 0, stream>>>(CC, bn2_g, bn2_b, ccbn);

  // kchunk = ceil(K / KB_SPLIT)
  k_skinny<66, 0><<<dim3(16, KB_SPLIT), dim3(256), 0, stream>>>(Xbuf, ccbn, Wq, partQ, FEATN, 209);
  k_reduce<66><<<dim3(66 * HHN / 256), dim3(256), 0, stream>>>(partQ, bq, qvbuf, KB_SPLIT, 0);
  k_skinny<2, 1><<<dim3(16, KB_SPLIT), dim3(256), 0, stream>>>(Xbuf, ccbn, Wk, partK, FEATN, 209);
  k_reduce<2><<<dim3(2 * HHN / 256), dim3(256), 0, stream>>>(partK, bk, kbuf, KB_SPLIT, 0);
  k_cross<<<dim3(BB), dim3(256), 0, stream>>>(qvbuf, kbuf, Xbuf);

  k_skinny<64, 2><<<dim3(16, KB_SPLIT), dim3(256), 0, stream>>>(Xbuf, ccbn, Wc1, partC, XW, 241);
  k_reduce<64><<<dim3(64 * HHN / 256), dim3(256), 0, stream>>>(partC, bc1, Rbuf, KB_SPLIT, 1);
  k_final<<<dim3(BB), dim3(256), 0, stream>>>(Rbuf, Wc2, bc2, out);

  (void)in_sizes; (void)n_in; (void)out_size; (void)ws_size;
}